// Round 13
// baseline (61.564 us; speedup 1.0000x reference)
//
#include <hip/hip_runtime.h>
#include <hip/hip_bf16.h>

// Problem constants (EdgeQProj): B=64, N=64, E=512, OBJ_DIM=2048, Q_DIM=1024,
// HID=512, KS=8. M_edges = B*E = 32768.
//
// Pipeline (identity: edge_logit[m] = P[b,src]+P[b,dst]):
//   pre_k  : blocks 0-511 gemm2 (q partials; independent of cvt) +
//            blocks 512-2559 cvt-A (node_feats -> A_bf16 swizzled) +
//            blocks 2560-3583 cvt-W (W_obj -> W_T bf16 swizzled)
//   gemm1  : node_h = relu(A_swz @ W_T^T + b). SINGLE-WAVE blocks (64 thr),
//            wave tile 64x64 (read:MFMA = 1:2), dbuf gl_lds, NO barriers,
//            counted s_waitcnt vmcnt(16) pipeline. 512 blocks = 2/CU.
//   tail_k : 64 blocks: reduce+bias+relu -> norms -> P-MFMA -> edges
//
// Swizzle (rule #21, both-sides, unchanged from R12): within each 64-elem
// (128B) k-chunk of a row, 16B slot g holds data of slot g ^ (row&7).
// gl_lds copies linearly; ds_read applies the same XOR.

using bf16x8 = __attribute__((ext_vector_type(8))) __bf16;
using f32x4  = __attribute__((ext_vector_type(4))) float;

__device__ __forceinline__ unsigned short f2bf(float f) {
    unsigned int u = __float_as_uint(f);
    unsigned int r = (u + 0x7FFFu + ((u >> 16) & 1u)) >> 16;  // RNE
    return (unsigned short)r;
}

__device__ __forceinline__ uint4 pk8u(f32x4 a, f32x4 b) {
    union { unsigned short us[8]; uint4 u4; } r;
    r.us[0] = f2bf(a[0]); r.us[1] = f2bf(a[1]); r.us[2] = f2bf(a[2]); r.us[3] = f2bf(a[3]);
    r.us[4] = f2bf(b[0]); r.us[5] = f2bf(b[1]); r.us[6] = f2bf(b[2]); r.us[7] = f2bf(b[3]);
    return r.u4;
}

__device__ __forceinline__ bf16x8 pk8(f32x4 a, f32x4 b) {
    union { uint4 u4; bf16x8 v; } r;
    r.u4 = pk8u(a, b);
    return r.v;
}

__device__ __forceinline__ void gl_lds16(const void* g, void* l) {
    __builtin_amdgcn_global_load_lds(
        (const __attribute__((address_space(1))) unsigned int*)g,
        (__attribute__((address_space(3))) unsigned int*)l,
        16, 0, 0);
}

// ---------------------------------------------------------------------------
// gemm2 body (R12-proven): part[z][64][4096] partial of q @ W_q.
// bid2: c-block = bid2 & 63 (64 cols), z = bid2 >> 6 (8 ksplits). 256 thr.
#define LDK2 136
__device__ __forceinline__ void gemm2_body(char* smem, int bid2, int t,
                                           const float* __restrict__ qf,
                                           const float* __restrict__ Wq,
                                           float* __restrict__ part) {
    auto Asm = reinterpret_cast<unsigned short(*)[LDK2]>(smem);                 // [64][136] q
    auto Bsm = reinterpret_cast<unsigned short(*)[LDK2]>(smem + 64 * LDK2 * 2); // [64][136] W^T

    int lane = t & 63, w = t >> 6;
    int l15 = lane & 15, l16 = lane >> 4;
    int c0 = (bid2 & 63) * 64;
    int k0 = (bid2 >> 6) * 128;

#pragma unroll
    for (int j = 0; j < 4; ++j) {
        int g = t + j * 256;
        int row = g >> 4, kc = g & 15;
        const float* src = qf + (size_t)row * 1024 + k0 + kc * 8;
        f32x4 v0 = *(const f32x4*)(src);
        f32x4 v1 = *(const f32x4*)(src + 4);
        *(uint4*)(&Asm[row][kc * 8]) = pk8u(v0, v1);
    }
    {
        int kg = t >> 4, cg = t & 15;        // 16 kg x 16 cg units (8k x 4c)
        f32x4 wv[8];
#pragma unroll
        for (int kk = 0; kk < 8; ++kk)
            wv[kk] = *(const f32x4*)(Wq + (size_t)(k0 + kg * 8 + kk) * 4096 + c0 + cg * 4);
#pragma unroll
        for (int cc = 0; cc < 4; ++cc) {
            union { unsigned short us[8]; uint4 u4; } p;
#pragma unroll
            for (int kk = 0; kk < 8; ++kk) p.us[kk] = f2bf(wv[kk][cc]);
            *(uint4*)(&Bsm[cg * 4 + cc][kg * 8]) = p.u4;
        }
    }
    __syncthreads();

    f32x4 acc[4];
#pragma unroll
    for (int i = 0; i < 4; ++i) acc[i] = (f32x4){0.f, 0.f, 0.f, 0.f};

#pragma unroll
    for (int ks = 0; ks < 4; ++ks) {
        bf16x8 bfr = *(const bf16x8*)(&Bsm[w * 16 + l15][ks * 32 + l16 * 8]);
#pragma unroll
        for (int i = 0; i < 4; ++i) {
            bf16x8 afr = *(const bf16x8*)(&Asm[i * 16 + l15][ks * 32 + l16 * 8]);
            acc[i] = __builtin_amdgcn_mfma_f32_16x16x32_bf16(afr, bfr, acc[i], 0, 0, 0);
        }
    }

    float* pz = part + (size_t)(bid2 >> 6) * 262144;
    int col = c0 + w * 16 + l15;
#pragma unroll
    for (int i = 0; i < 4; ++i)
#pragma unroll
        for (int j = 0; j < 4; ++j) {
            int row = i * 16 + l16 * 4 + j;
            pz[(size_t)row * 4096 + col] = acc[i][j];
        }
}

// ---------------------------------------------------------------------------
// 1) pre_k: gemm2 (g2n blocks) + cvt-A (2048) + cvt-W (1024), all independent.
__global__ __launch_bounds__(256) void pre_k(const float* __restrict__ nf,
                                             const float* __restrict__ W,
                                             unsigned short* __restrict__ A,
                                             unsigned short* __restrict__ WT,
                                             const float* __restrict__ qf,
                                             const float* __restrict__ Wq,
                                             float* __restrict__ part, int g2n) {
    __shared__ __align__(16) char smem[34816];
    int bid = blockIdx.x, t = threadIdx.x;
    if (bid < g2n) {
        gemm2_body(smem, bid, t, qf, Wq, part);
        return;
    }
    int cb = bid - g2n;
    if (cb < 2048) {
        // ---- A convert+swizzle: chunk=64 elems, 8 slots, slot^=(row&7) ----
        int tid = cb * 256 + t;
        for (int p = tid; p < 1048576; p += 524288) {
            int r = p >> 8;
            int grp = p & 255;
            int chunk = grp >> 3, slot = grp & 7;
            int sslot = slot ^ (r & 7);
            const float* src = nf + (size_t)r * 2048 + chunk * 64 + sslot * 8;
            f32x4 v0 = *(const f32x4*)(src);
            f32x4 v1 = *(const f32x4*)(src + 4);
            *(uint4*)(A + (size_t)r * 2048 + chunk * 64 + slot * 8) = pk8u(v0, v1);
        }
    } else {
        // ---- W_T transpose + convert + swizzle ----
        auto lds = reinterpret_cast<float(*)[33]>(smem);   // [32][33]
        int g = cb - 2048;
        int k0 = (g & 63) * 32, n0 = (g >> 6) * 32;
        int tx = t & 31, ty = t >> 5;
#pragma unroll
        for (int j = 0; j < 4; ++j)
            lds[ty + j * 8][tx] = W[(size_t)(k0 + ty + j * 8) * 512 + n0 + tx];
        __syncthreads();
#pragma unroll
        for (int j = 0; j < 4; ++j) {
            int n = n0 + ty + j * 8;
            int k = k0 + tx;
            int chunk = k >> 6, off = k & 63;
            int ksw = chunk * 64 + (((off >> 3) ^ (n & 7)) << 3) + (k & 7);
            WT[(size_t)n * 2048 + ksw] = f2bf(lds[tx][ty + j * 8]);
        }
    }
}

// ---------------------------------------------------------------------------
// 2) gemm1: node_h[4096][512](fp32) = relu(A_swz @ W_T^T + b).
//    SINGLE-WAVE blocks: 64 thr, wave tile 64x64 (4x4 frags of 16x16x32),
//    BK=64, dbuf 32KB, grid 512 = 2 blocks/CU, ALL co-resident.
//    No __syncthreads anywhere: wave-private counted-vmcnt pipeline —
//    issue STAGE(next) (16 gl_lds), then s_waitcnt vmcnt(16) waits only for
//    the PREVIOUS step's 16 loads; next-tile loads stay in flight under
//    this step's 16 ds_read_b128 + 32 MFMAs (T4, m218 pattern; rule #18
//    sched_barrier after the asm wait).
__global__ __launch_bounds__(64) void gemm1(const unsigned short* __restrict__ A,
                                            const unsigned short* __restrict__ BT,
                                            const float* __restrict__ bias,
                                            float* __restrict__ C) {
    __shared__ __align__(16) unsigned short Asm[2][64 * 64];
    __shared__ __align__(16) unsigned short Bsm[2][64 * 64];

    // XCD swizzle over 512 blocks (bijective): per-XCD 8 m-panels (2MB) + B (2MB).
    int bid = blockIdx.x;
    int swz = (bid & 7) * 64 + (bid >> 3);
    int m0 = (swz >> 3) * 64, n0 = (swz & 7) * 64;

    int lane = threadIdx.x;
    int l15 = lane & 15, l16 = lane >> 4;

    // staging: chunk = 8 rows x 128B; lane l -> row l>>3, slot l&7 (linear).
    const unsigned short* aG = A  + (size_t)(m0 + (lane >> 3)) * 2048 + (lane & 7) * 8;
    const unsigned short* bG = BT + (size_t)(n0 + (lane >> 3)) * 2048 + (lane & 7) * 8;

    f32x4 acc[4][4];
#pragma unroll
    for (int i = 0; i < 4; ++i)
#pragma unroll
        for (int j = 0; j < 4; ++j) acc[i][j] = (f32x4){0.f, 0.f, 0.f, 0.f};

#define G1_STAGE(buf, step)                                                    \
    do {                                                                       \
        int _ko = (step) * 64;                                                 \
        _Pragma("unroll")                                                      \
        for (int _i = 0; _i < 8; ++_i)                                         \
            gl_lds16(aG + (size_t)(_i * 8) * 2048 + _ko, &Asm[buf][_i * 512]); \
        _Pragma("unroll")                                                      \
        for (int _i = 0; _i < 8; ++_i)                                         \
            gl_lds16(bG + (size_t)(_i * 8) * 2048 + _ko, &Bsm[buf][_i * 512]); \
    } while (0)

    G1_STAGE(0, 0);

    for (int s = 0; s < 32; ++s) {
        int cur = s & 1;
        if (s < 31) {
            G1_STAGE(cur ^ 1, s + 1);                    // 16 new loads in flight
            asm volatile("s_waitcnt vmcnt(16)" ::: "memory");  // wait prev 16 only
        } else {
            asm volatile("s_waitcnt vmcnt(0)" ::: "memory");
        }
        __builtin_amdgcn_sched_barrier(0);

        const char* Ab = (const char*)Asm[cur];
        const char* Bb = (const char*)Bsm[cur];
#pragma unroll
        for (int ks = 0; ks < 2; ++ks) {
            int sx = ((ks * 4 + l16) ^ (l15 & 7)) << 4;  // swizzled byte slot
            bf16x8 af[4], bf[4];
#pragma unroll
            for (int fm = 0; fm < 4; ++fm)
                af[fm] = *(const bf16x8*)(Ab + (fm * 16 + l15) * 128 + sx);
#pragma unroll
            for (int fn = 0; fn < 4; ++fn)
                bf[fn] = *(const bf16x8*)(Bb + (fn * 16 + l15) * 128 + sx);
#pragma unroll
            for (int fm = 0; fm < 4; ++fm)
#pragma unroll
                for (int fn = 0; fn < 4; ++fn)
                    acc[fm][fn] = __builtin_amdgcn_mfma_f32_16x16x32_bf16(
                        af[fm], bf[fn], acc[fm][fn], 0, 0, 0);
        }
    }
#undef G1_STAGE

    // epilogue: bias + relu -> fp32; D layout col=lane&15, row=(lane>>4)*4+j
#pragma unroll
    for (int fm = 0; fm < 4; ++fm)
#pragma unroll
        for (int fn = 0; fn < 4; ++fn) {
            int col = n0 + fn * 16 + l15;
            float bv = bias[col];
#pragma unroll
            for (int j = 0; j < 4; ++j) {
                int row = m0 + fm * 16 + l16 * 4 + j;
                float v = acc[fm][fn][j] + bv;
                C[(size_t)row * 512 + col] = v > 0.f ? v : 0.f;
            }
        }
}

// fallback wrapper (sequential path)
__global__ __launch_bounds__(256) void gemm2_only(const float* qf, const float* Wq,
                                                  float* part) {
    __shared__ __align__(16) char smem[34816];
    gemm2_body(smem, blockIdx.x, threadIdx.x, qf, Wq, part);
}

// ---------------------------------------------------------------------------
// 3) tail_k: one block per batch (64 x 256 thr). reduce+bias+relu -> norms ->
//    P-MFMA -> 512 edge gather-adds.
__global__ __launch_bounds__(256) void tail_k(const float* __restrict__ part,
                                              const float* __restrict__ bq,
                                              const float* __restrict__ node_h,
                                              const int* __restrict__ idxs,
                                              float* __restrict__ out) {
    __shared__ float qs[4096];
    __shared__ float red[4][8];
    __shared__ float inv[8];
    __shared__ float Pl[64][8];

    int b = blockIdx.x, t = threadIdx.x;
    int lane = t & 63, w = t >> 6;
    int l15 = lane & 15, l16 = lane >> 4;

    // ---- phase 1: reduce k-split partials + bias + relu ----
#pragma unroll
    for (int j = 0; j < 4; ++j) {
        int c = j * 1024 + t * 4;
        f32x4 a = (f32x4){0.f, 0.f, 0.f, 0.f};
#pragma unroll
        for (int z = 0; z < 8; ++z)
            a += *(const f32x4*)(part + (size_t)z * 262144 + (size_t)b * 4096 + c);
        f32x4 bb = *(const f32x4*)(bq + c);
#pragma unroll
        for (int i = 0; i < 4; ++i) {
            float v = a[i] + bb[i];
            a[i] = v > 0.f ? v : 0.f;
        }
        *(f32x4*)(&qs[c]) = a;
    }
    __syncthreads();

    // ---- phase 2: per-k norms ----
    {
        const float* row = qs + t * 16;
        float sq[8] = {0.f, 0.f, 0.f, 0.f, 0.f, 0.f, 0.f, 0.f};
#pragma unroll
        for (int j = 0; j < 4; ++j) {
            f32x4 v = *(const f32x4*)(row + j * 4);
            sq[(j * 4 + 0) & 7] += v[0] * v[0];
            sq[(j * 4 + 1) & 7] += v[1] * v[1];
            sq[(j * 4 + 2) & 7] += v[2] * v[2];
            sq[(j * 4 + 3) & 7] += v[3] * v[3];
        }
#pragma unroll
        for (int k = 0; k < 8; ++k) {
            float v = sq[k];
            v += __shfl_xor(v, 1);  v += __shfl_xor(v, 2);  v += __shfl_xor(v, 4);
            v += __shfl_xor(v, 8);  v += __shfl_xor(v, 16); v += __shfl_xor(v, 32);
            sq[k] = v;
        }
        if (lane == 0) {
#pragma unroll
            for (int k = 0; k < 8; ++k) red[w][k] = sq[k];
        }
    }
    __syncthreads();
    if (t < 8) {
        float s = red[0][t] + red[1][t] + red[2][t] + red[3][t];
        inv[t] = 1.0f / sqrtf(s);
    }
    __syncthreads();

    // ---- phase 3: P = (node_h[b] @ q_e) * inv  (MFMA 16x16x32, N=8 used) --
    {
        bool active = l15 < 8;
        float invv = active ? inv[l15] : 0.f;
        const float* arow = node_h + (size_t)(b * 64 + w * 16 + l15) * 512 + l16 * 8;
        f32x4 acc = (f32x4){0.f, 0.f, 0.f, 0.f};
#pragma unroll
        for (int kt = 0; kt < 16; ++kt) {
            f32x4 v0 = *(const f32x4*)(arow + kt * 32);
            f32x4 v1 = *(const f32x4*)(arow + kt * 32 + 4);
            bf16x8 af = pk8(v0, v1);
            union { unsigned short us[8]; bf16x8 v; } bqf;
#pragma unroll
            for (int i = 0; i < 8; ++i)
                bqf.us[i] = active ? f2bf(qs[kt * 256 + (l16 * 8 + i) * 8 + l15]) : 0;
            acc = __builtin_amdgcn_mfma_f32_16x16x32_bf16(af, bqf.v, acc, 0, 0, 0);
        }
        if (active) {
#pragma unroll
            for (int j = 0; j < 4; ++j)
                Pl[w * 16 + l16 * 4 + j][l15] = acc[j] * invv;
        }
    }
    __syncthreads();

    // ---- phase 4: 512 edges of batch b, 2 per thread ----
#pragma unroll
    for (int e = 0; e < 2; ++e) {
        int m = b * 512 + e * 256 + t;
        int idx = idxs[m];
        int r = idx & 4095;
        int src = r >> 6, dst = r & 63;
        f32x4 o0 = *(const f32x4*)(&Pl[src][0]) + *(const f32x4*)(&Pl[dst][0]);
        f32x4 o1 = *(const f32x4*)(&Pl[src][4]) + *(const f32x4*)(&Pl[dst][4]);
        *(f32x4*)(out + (size_t)m * 8)     = o0;
        *(f32x4*)(out + (size_t)m * 8 + 4) = o1;
    }
}

// ---------------------------------------------------------------------------
extern "C" void kernel_launch(void* const* d_in, const int* in_sizes, int n_in,
                              void* d_out, int out_size, void* d_ws, size_t ws_size,
                              hipStream_t stream) {
    const float* node_feats = (const float*)d_in[0];  // [64][64][2048]
    const float* q_feats    = (const float*)d_in[1];  // [64][1024]
    const int*   indexes    = (const int*)d_in[2];    // [32768]
    const float* W_obj      = (const float*)d_in[3];  // [2048][512]
    const float* b_obj      = (const float*)d_in[4];  // [512]
    const float* W_q        = (const float*)d_in[5];  // [1024][4096]
    const float* b_q        = (const float*)d_in[6];  // [4096]
    float* out = (float*)d_out;                       // [32768][8]

    char* ws = (char*)d_ws;
    unsigned short* A_swz = (unsigned short*)(ws + 0);         // 16.78MB
    unsigned short* W_T   = (unsigned short*)(ws + 16777216);  // 2.10MB
    float* node_h         = (float*)(ws + 18874368);           // 8.39MB

    if (ws_size >= 35651584ull) {
        // concurrent layout: part has its own region
        float* part = (float*)(ws + 27262976);                 // 8.39MB
        pre_k<<<3584, 256, 0, stream>>>(node_feats, W_obj, A_swz, W_T,
                                        q_feats, W_q, part, 512);
        gemm1<<<512, 64, 0, stream>>>(A_swz, W_T, b_obj, node_h);
        tail_k<<<64, 256, 0, stream>>>(part, b_q, node_h, indexes, out);
    } else {
        // sequential fallback: part aliases A_swz (gemm2 after gemm1)
        float* part = (float*)(ws + 0);
        pre_k<<<3072, 256, 0, stream>>>(node_feats, W_obj, A_swz, W_T,
                                        q_feats, W_q, nullptr, 0);
        gemm1<<<512, 64, 0, stream>>>(A_swz, W_T, b_obj, node_h);
        gemm2_only<<<512, 256, 0, stream>>>(q_feats, W_q, part);
        tail_k<<<64, 256, 0, stream>>>(part, b_q, node_h, indexes, out);
    }
}

// Round 14
// 49.082 us; speedup vs baseline: 1.2543x; 1.2543x over previous
//
#include <hip/hip_runtime.h>
#include <hip/hip_bf16.h>

// Problem constants (EdgeQProj): B=64, N=64, E=512, OBJ_DIM=2048, Q_DIM=1024,
// HID=512, KS=8. M_edges = B*E = 32768.
//
// Pipeline (identity: edge_logit[m] = P[b,src]+P[b,dst]):
//   pre_k  : blocks 0-255 gemm2 (128-wide q partials, R10 body) +
//            blocks 256-2303 cvt-A (node_feats -> A_bf16, 16-slot swizzle) +
//            blocks 2304-3327 cvt-W (W_obj -> W_T bf16, swizzled)
//   gemm1  : node_h = relu(A_swz @ W_T^T + b). R10 body VERBATIM:
//            BM64/BN64/BK128, 4 waves 2x2 (32x32 tiles), 64KB dbuf gl_lds,
//            512 blocks = 2/CU all co-resident.
//   tail_k : 64 blocks: reduce+bias+relu -> norms -> P-MFMA -> edges
//
// Swizzle (rule #21, both-sides, R10's 16-slot): within each 128-elem (256B)
// k-chunk of a row, 16B slot g holds data of slot g ^ (row&15). gl_lds
// copies linearly; gemm1's ds_read applies the same XOR (2 lanes/bank, free).

using bf16x8 = __attribute__((ext_vector_type(8))) __bf16;
using f32x4  = __attribute__((ext_vector_type(4))) float;

__device__ __forceinline__ unsigned short f2bf(float f) {
    unsigned int u = __float_as_uint(f);
    unsigned int r = (u + 0x7FFFu + ((u >> 16) & 1u)) >> 16;  // RNE
    return (unsigned short)r;
}

__device__ __forceinline__ uint4 pk8u(f32x4 a, f32x4 b) {
    union { unsigned short us[8]; uint4 u4; } r;
    r.us[0] = f2bf(a[0]); r.us[1] = f2bf(a[1]); r.us[2] = f2bf(a[2]); r.us[3] = f2bf(a[3]);
    r.us[4] = f2bf(b[0]); r.us[5] = f2bf(b[1]); r.us[6] = f2bf(b[2]); r.us[7] = f2bf(b[3]);
    return r.u4;
}

__device__ __forceinline__ bf16x8 pk8(f32x4 a, f32x4 b) {
    union { uint4 u4; bf16x8 v; } r;
    r.u4 = pk8u(a, b);
    return r.v;
}

__device__ __forceinline__ void gl_lds16(const void* g, void* l) {
    __builtin_amdgcn_global_load_lds(
        (const __attribute__((address_space(1))) unsigned int*)g,
        (__attribute__((address_space(3))) unsigned int*)l,
        16, 0, 0);
}

// ---------------------------------------------------------------------------
// gemm2 body (R10-proven, 128-wide): part[z][64][4096] partial of q @ W_q.
// bid2 0..255: c0 = (bid2&31)*128, z = bid2>>5. 256 thr (4 waves).
#define LDK2 136
__device__ __forceinline__ void gemm2_body(char* smem, int bid2, int t,
                                           const float* __restrict__ qf,
                                           const float* __restrict__ Wq,
                                           float* __restrict__ part) {
    auto Asm = reinterpret_cast<unsigned short(*)[LDK2]>(smem);                 // [64][136]  q
    auto Bsm = reinterpret_cast<unsigned short(*)[LDK2]>(smem + 64 * LDK2 * 2); // [128][136] W^T

    int lane = t & 63, w = t >> 6;
    int l15 = lane & 15, l16 = lane >> 4;
    int c0 = (bid2 & 31) * 128;
    int k0 = (bid2 >> 5) * 128;

    // ---- stage A: q[64][k0:k0+128] fp32 -> bf16 ----
#pragma unroll
    for (int j = 0; j < 4; ++j) {
        int g = t + j * 256;
        int row = g >> 4, kc = g & 15;
        const float* src = qf + (size_t)row * 1024 + k0 + kc * 8;
        f32x4 v0 = *(const f32x4*)(src);
        f32x4 v1 = *(const f32x4*)(src + 4);
        *(uint4*)(&Asm[row][kc * 8]) = pk8u(v0, v1);
    }
    // ---- stage B: W_q[k0:k0+128][c0:c0+128] fp32 -> bf16, transposed ----
#pragma unroll
    for (int j = 0; j < 2; ++j) {
        int g = t + j * 256;
        int kg = g >> 5, cg = g & 31;
        f32x4 wv[8];
#pragma unroll
        for (int kk = 0; kk < 8; ++kk)
            wv[kk] = *(const f32x4*)(Wq + (size_t)(k0 + kg * 8 + kk) * 4096 + c0 + cg * 4);
#pragma unroll
        for (int cc = 0; cc < 4; ++cc) {
            union { unsigned short us[8]; uint4 u4; } p;
#pragma unroll
            for (int kk = 0; kk < 8; ++kk) p.us[kk] = f2bf(wv[kk][cc]);
            *(uint4*)(&Bsm[cg * 4 + cc][kg * 8]) = p.u4;
        }
    }
    __syncthreads();

    // ---- MFMA: wave w covers cols [w*32, w*32+32); 4m x 2n x 4k frags ----
    f32x4 acc[4][2];
#pragma unroll
    for (int i = 0; i < 4; ++i)
#pragma unroll
        for (int j = 0; j < 2; ++j) acc[i][j] = (f32x4){0.f, 0.f, 0.f, 0.f};

#pragma unroll
    for (int ks = 0; ks < 4; ++ks) {
        bf16x8 bfr[2];
#pragma unroll
        for (int jn = 0; jn < 2; ++jn)
            bfr[jn] = *(const bf16x8*)(&Bsm[w * 32 + jn * 16 + l15][ks * 32 + l16 * 8]);
#pragma unroll
        for (int i = 0; i < 4; ++i) {
            bf16x8 afr = *(const bf16x8*)(&Asm[i * 16 + l15][ks * 32 + l16 * 8]);
            acc[i][0] = __builtin_amdgcn_mfma_f32_16x16x32_bf16(afr, bfr[0], acc[i][0], 0, 0, 0);
            acc[i][1] = __builtin_amdgcn_mfma_f32_16x16x32_bf16(afr, bfr[1], acc[i][1], 0, 0, 0);
        }
    }

    // ---- write partials ----
    float* pz = part + (size_t)(bid2 >> 5) * 262144;
#pragma unroll
    for (int i = 0; i < 4; ++i)
#pragma unroll
        for (int jn = 0; jn < 2; ++jn) {
            int col = c0 + w * 32 + jn * 16 + l15;
#pragma unroll
            for (int j = 0; j < 4; ++j) {
                int row = i * 16 + l16 * 4 + j;
                pz[(size_t)row * 4096 + col] = acc[i][jn][j];
            }
        }
}

// ---------------------------------------------------------------------------
// 1) pre_k: gemm2 (g2n blocks, dispatched first) + cvt-A (2048) + cvt-W (1024).
//    All parts independent: gemm2{qf,Wq->part}, cvt{nf,W->A,WT}.
__global__ __launch_bounds__(256) void pre_k(const float* __restrict__ nf,
                                             const float* __restrict__ W,
                                             unsigned short* __restrict__ A,
                                             unsigned short* __restrict__ WT,
                                             const float* __restrict__ qf,
                                             const float* __restrict__ Wq,
                                             float* __restrict__ part, int g2n) {
    __shared__ __align__(16) char smem[52224];
    int bid = blockIdx.x, t = threadIdx.x;
    if (bid < g2n) {
        gemm2_body(smem, bid, t, qf, Wq, part);
        return;
    }
    int cb = bid - g2n;
    if (cb < 2048) {
        // ---- A convert+swizzle (R10): chunk=128 elems, 16 slots of 16B ----
        int tid = cb * 256 + t;
        for (int p = tid; p < 1048576; p += 524288) {
            int r = p >> 8;                           // row 0..4095
            int grp = p & 255;
            int chunk = grp >> 4, slot = grp & 15;
            int sslot = slot ^ (r & 15);
            const float* src = nf + (size_t)r * 2048 + chunk * 128 + sslot * 8;
            f32x4 v0 = *(const f32x4*)(src);
            f32x4 v1 = *(const f32x4*)(src + 4);
            *(uint4*)(A + (size_t)r * 2048 + chunk * 128 + slot * 8) = pk8u(v0, v1);
        }
    } else {
        // ---- W_T transpose + convert + swizzle (R10) ----
        auto lds = reinterpret_cast<float(*)[33]>(smem);   // [32][33]
        int g = cb - 2048;                            // 0..1023
        int k0 = (g & 63) * 32, n0 = (g >> 6) * 32;
        int tx = t & 31, ty = t >> 5;
#pragma unroll
        for (int j = 0; j < 4; ++j)
            lds[ty + j * 8][tx] = W[(size_t)(k0 + ty + j * 8) * 512 + n0 + tx];
        __syncthreads();
#pragma unroll
        for (int j = 0; j < 4; ++j) {
            int n = n0 + ty + j * 8;
            int k = k0 + tx;
            int chunk = k >> 7, off = k & 127;
            int ksw = chunk * 128 + (((off >> 3) ^ (n & 15)) << 3) + (off & 7);
            WT[(size_t)n * 2048 + ksw] = f2bf(lds[tx][ty + j * 8]);
        }
    }
}

// ---------------------------------------------------------------------------
// 2) gemm1 (R10 body VERBATIM): node_h[4096][512](fp32) = relu(A_swz@W_T^T+b).
//    BM=64 BN=64 BK=128, 256 thr (4 waves 2x2 of 32x32), grid 512 = 2/CU.
//    Double-buffered gl_lds LDS (64KB); stage(next) issued before compute;
//    one __syncthreads per step (vmcnt drain lands a full compute-phase
//    after issue); swizzled ds_read.
__global__ __launch_bounds__(256) void gemm1(const unsigned short* __restrict__ A,
                                             const unsigned short* __restrict__ BT,
                                             const float* __restrict__ bias,
                                             float* __restrict__ C) {
    __shared__ __align__(16) unsigned short AsmB[2 * 64 * 128];
    __shared__ __align__(16) unsigned short BsmB[2 * 64 * 128];

    // XCD swizzle over 512 blocks (bijective). per-XCD: 8 A m-panels + full B.
    int g1 = blockIdx.x;
    int swz = (g1 & 7) * 64 + (g1 >> 3);
    int by = swz >> 3, bx = swz & 7;          // by 0..63, bx 0..7
    int m0 = by * 64, n0 = bx * 64;

    int t = threadIdx.x;
    int lane = t & 63, w = t >> 6;
    int wm = w >> 1, wn = w & 1;              // wave grid 2x2
    int l15 = lane & 15, l16 = lane >> 4;

    // staging: chunk = 4 rows x 256B; lane l -> row l>>4, 16B slot l&15
    // (LDS byte off = l*16, linear = gl_lds contract).
    int srow = lane >> 4, scol = (lane & 15) * 8;
    const unsigned short* aG = A  + (size_t)(m0 + w * 16 + srow) * 2048 + scol;
    const unsigned short* bG = BT + (size_t)(n0 + w * 16 + srow) * 2048 + scol;

    f32x4 acc[2][2];
#pragma unroll
    for (int i = 0; i < 2; ++i)
#pragma unroll
        for (int j = 0; j < 2; ++j) acc[i][j] = (f32x4){0.f, 0.f, 0.f, 0.f};

#define G1_STAGE(buf, step)                                                    \
    do {                                                                       \
        int _ko = (step) * 128;                                                \
        unsigned short* _aL = AsmB + (buf) * 8192 + (w * 16) * 128;            \
        unsigned short* _bL = BsmB + (buf) * 8192 + (w * 16) * 128;            \
        _Pragma("unroll")                                                      \
        for (int _i = 0; _i < 4; ++_i) {                                       \
            gl_lds16(aG + (size_t)(_i * 4) * 2048 + _ko, _aL + (_i * 4) * 128);\
            gl_lds16(bG + (size_t)(_i * 4) * 2048 + _ko, _bL + (_i * 4) * 128);\
        }                                                                      \
    } while (0)

    G1_STAGE(0, 0);
    __syncthreads();

    for (int s = 0; s < 16; ++s) {
        int cur = s & 1;
        if (s < 15) G1_STAGE(cur ^ 1, s + 1);   // issue next-tile loads first

        const char* Ab = (const char*)(AsmB + cur * 8192);
        const char* Bb = (const char*)(BsmB + cur * 8192);
#pragma unroll
        for (int ks = 0; ks < 4; ++ks) {
            int co = ks * 64 + l16 * 16;        // byte col within 256B row
            int r0 = wm * 32 + l15, r1 = r0 + 16;
            int c0n = wn * 32 + l15, c1n = c0n + 16;
            bf16x8 a0 = *(const bf16x8*)(Ab + r0 * 256 + (co ^ ((r0 & 15) << 4)));
            bf16x8 a1 = *(const bf16x8*)(Ab + r1 * 256 + (co ^ ((r1 & 15) << 4)));
            bf16x8 b0 = *(const bf16x8*)(Bb + c0n * 256 + (co ^ ((c0n & 15) << 4)));
            bf16x8 b1 = *(const bf16x8*)(Bb + c1n * 256 + (co ^ ((c1n & 15) << 4)));
            acc[0][0] = __builtin_amdgcn_mfma_f32_16x16x32_bf16(a0, b0, acc[0][0], 0, 0, 0);
            acc[0][1] = __builtin_amdgcn_mfma_f32_16x16x32_bf16(a0, b1, acc[0][1], 0, 0, 0);
            acc[1][0] = __builtin_amdgcn_mfma_f32_16x16x32_bf16(a1, b0, acc[1][0], 0, 0, 0);
            acc[1][1] = __builtin_amdgcn_mfma_f32_16x16x32_bf16(a1, b1, acc[1][1], 0, 0, 0);
        }
        __syncthreads();
    }
#undef G1_STAGE

    // epilogue: bias + relu -> fp32; D layout col=lane&15, row=(lane>>4)*4+j
#pragma unroll
    for (int fm = 0; fm < 2; ++fm)
#pragma unroll
        for (int fn = 0; fn < 2; ++fn) {
            int col = n0 + wn * 32 + fn * 16 + l15;
            float bv = bias[col];
#pragma unroll
            for (int j = 0; j < 4; ++j) {
                int row = m0 + wm * 32 + fm * 16 + l16 * 4 + j;
                float v = acc[fm][fn][j] + bv;
                C[(size_t)row * 512 + col] = v > 0.f ? v : 0.f;
            }
        }
}

// fallback wrapper (sequential path)
__global__ __launch_bounds__(256) void gemm2_only(const float* qf, const float* Wq,
                                                  float* part) {
    __shared__ __align__(16) char smem[52224];
    gemm2_body(smem, blockIdx.x, threadIdx.x, qf, Wq, part);
}

// ---------------------------------------------------------------------------
// 3) tail_k: one block per batch (64 x 256 thr). reduce+bias+relu -> norms ->
//    P-MFMA -> 512 edge gather-adds.
__global__ __launch_bounds__(256) void tail_k(const float* __restrict__ part,
                                              const float* __restrict__ bq,
                                              const float* __restrict__ node_h,
                                              const int* __restrict__ idxs,
                                              float* __restrict__ out) {
    __shared__ float qs[4096];
    __shared__ float red[4][8];
    __shared__ float inv[8];
    __shared__ float Pl[64][8];

    int b = blockIdx.x, t = threadIdx.x;
    int lane = t & 63, w = t >> 6;
    int l15 = lane & 15, l16 = lane >> 4;

    // ---- phase 1: reduce k-split partials + bias + relu ----
#pragma unroll
    for (int j = 0; j < 4; ++j) {
        int c = j * 1024 + t * 4;
        f32x4 a = (f32x4){0.f, 0.f, 0.f, 0.f};
#pragma unroll
        for (int z = 0; z < 8; ++z)
            a += *(const f32x4*)(part + (size_t)z * 262144 + (size_t)b * 4096 + c);
        f32x4 bb = *(const f32x4*)(bq + c);
#pragma unroll
        for (int i = 0; i < 4; ++i) {
            float v = a[i] + bb[i];
            a[i] = v > 0.f ? v : 0.f;
        }
        *(f32x4*)(&qs[c]) = a;
    }
    __syncthreads();

    // ---- phase 2: per-k norms ----
    {
        const float* row = qs + t * 16;
        float sq[8] = {0.f, 0.f, 0.f, 0.f, 0.f, 0.f, 0.f, 0.f};
#pragma unroll
        for (int j = 0; j < 4; ++j) {
            f32x4 v = *(const f32x4*)(row + j * 4);
            sq[(j * 4 + 0) & 7] += v[0] * v[0];
            sq[(j * 4 + 1) & 7] += v[1] * v[1];
            sq[(j * 4 + 2) & 7] += v[2] * v[2];
            sq[(j * 4 + 3) & 7] += v[3] * v[3];
        }
#pragma unroll
        for (int k = 0; k < 8; ++k) {
            float v = sq[k];
            v += __shfl_xor(v, 1);  v += __shfl_xor(v, 2);  v += __shfl_xor(v, 4);
            v += __shfl_xor(v, 8);  v += __shfl_xor(v, 16); v += __shfl_xor(v, 32);
            sq[k] = v;
        }
        if (lane == 0) {
#pragma unroll
            for (int k = 0; k < 8; ++k) red[w][k] = sq[k];
        }
    }
    __syncthreads();
    if (t < 8) {
        float s = red[0][t] + red[1][t] + red[2][t] + red[3][t];
        inv[t] = 1.0f / sqrtf(s);
    }
    __syncthreads();

    // ---- phase 3: P = (node_h[b] @ q_e) * inv  (MFMA 16x16x32, N=8 used) --
    {
        bool active = l15 < 8;
        float invv = active ? inv[l15] : 0.f;
        const float* arow = node_h + (size_t)(b * 64 + w * 16 + l15) * 512 + l16 * 8;
        f32x4 acc = (f32x4){0.f, 0.f, 0.f, 0.f};
#pragma unroll
        for (int kt = 0; kt < 16; ++kt) {
            f32x4 v0 = *(const f32x4*)(arow + kt * 32);
            f32x4 v1 = *(const f32x4*)(arow + kt * 32 + 4);
            bf16x8 af = pk8(v0, v1);
            union { unsigned short us[8]; bf16x8 v; } bqf;
#pragma unroll
            for (int i = 0; i < 8; ++i)
                bqf.us[i] = active ? f2bf(qs[kt * 256 + (l16 * 8 + i) * 8 + l15]) : 0;
            acc = __builtin_amdgcn_mfma_f32_16x16x32_bf16(af, bqf.v, acc, 0, 0, 0);
        }
        if (active) {
#pragma unroll
            for (int j = 0; j < 4; ++j)
                Pl[w * 16 + l16 * 4 + j][l15] = acc[j] * invv;
        }
    }
    __syncthreads();

    // ---- phase 4: 512 edges of batch b, 2 per thread ----
#pragma unroll
    for (int e = 0; e < 2; ++e) {
        int m = b * 512 + e * 256 + t;
        int idx = idxs[m];
        int r = idx & 4095;
        int src = r >> 6, dst = r & 63;
        f32x4 o0 = *(const f32x4*)(&Pl[src][0]) + *(const f32x4*)(&Pl[dst][0]);
        f32x4 o1 = *(const f32x4*)(&Pl[src][4]) + *(const f32x4*)(&Pl[dst][4]);
        *(f32x4*)(out + (size_t)m * 8)     = o0;
        *(f32x4*)(out + (size_t)m * 8 + 4) = o1;
    }
}

// ---------------------------------------------------------------------------
extern "C" void kernel_launch(void* const* d_in, const int* in_sizes, int n_in,
                              void* d_out, int out_size, void* d_ws, size_t ws_size,
                              hipStream_t stream) {
    const float* node_feats = (const float*)d_in[0];  // [64][64][2048]
    const float* q_feats    = (const float*)d_in[1];  // [64][1024]
    const int*   indexes    = (const int*)d_in[2];    // [32768]
    const float* W_obj      = (const float*)d_in[3];  // [2048][512]
    const float* b_obj      = (const float*)d_in[4];  // [512]
    const float* W_q        = (const float*)d_in[5];  // [1024][4096]
    const float* b_q        = (const float*)d_in[6];  // [4096]
    float* out = (float*)d_out;                       // [32768][8]

    char* ws = (char*)d_ws;
    unsigned short* A_swz = (unsigned short*)(ws + 0);         // 16.78MB
    unsigned short* W_T   = (unsigned short*)(ws + 16777216);  // 2.10MB
    float* node_h         = (float*)(ws + 18874368);           // 8.39MB

    if (ws_size >= 35651584ull) {
        // concurrent layout: part has its own region
        float* part = (float*)(ws + 27262976);                 // 8.39MB
        pre_k<<<3328, 256, 0, stream>>>(node_feats, W_obj, A_swz, W_T,
                                        q_feats, W_q, part, 256);
        gemm1<<<512, 256, 0, stream>>>(A_swz, W_T, b_obj, node_h);
        tail_k<<<64, 256, 0, stream>>>(part, b_q, node_h, indexes, out);
    } else {
        // sequential fallback: part aliases A_swz (gemm2 after gemm1)
        float* part = (float*)(ws + 0);
        pre_k<<<3072, 256, 0, stream>>>(node_feats, W_obj, A_swz, W_T,
                                        q_feats, W_q, nullptr, 0);
        gemm1<<<512, 256, 0, stream>>>(A_swz, W_T, b_obj, node_h);
        gemm2_only<<<256, 256, 0, stream>>>(q_feats, W_q, part);
        tail_k<<<64, 256, 0, stream>>>(part, b_q, node_h, indexes, out);
    }
}

// Round 15
// 43.397 us; speedup vs baseline: 1.4186x; 1.1310x over previous
//
#include <hip/hip_runtime.h>
#include <hip/hip_bf16.h>

// Problem constants (EdgeQProj): B=64, N=64, E=512, OBJ_DIM=2048, Q_DIM=1024,
// HID=512, KS=8. M_edges = B*E = 32768.
//
// R10 structure RESTORED (measured best: 43.2us). Only delta: s_setprio(1)
// around gemm1's MFMA cluster (T5).
//
// Pipeline (identity: edge_logit[m] = P[b,src]+P[b,dst]):
//   cvt_k     : node_feats -> A_bf16 (SWIZZLED), W_obj -> W_T bf16 (SWIZZLED)
//   gemm_fused: blocks 0-255 = gemm2 (q partials), 256-767 = gemm1 (node_h)
//               -- heterogeneous pairing is worth ~6us (R14 isolation)
//   tail_k    : per-batch reduce+bias+relu -> norms -> P-MFMA -> edges
//
// Swizzle (rule #21, both-sides): within each 128-elem (256B) k-chunk of a
// row, 16B slot g holds data of slot g ^ (row&15). gl_lds copies linearly;
// gemm1's ds_read applies the same XOR -> 64 lanes spread over all 32 banks.

using bf16x8 = __attribute__((ext_vector_type(8))) __bf16;
using f32x4  = __attribute__((ext_vector_type(4))) float;

__device__ __forceinline__ unsigned short f2bf(float f) {
    unsigned int u = __float_as_uint(f);
    unsigned int r = (u + 0x7FFFu + ((u >> 16) & 1u)) >> 16;  // RNE
    return (unsigned short)r;
}

__device__ __forceinline__ uint4 pk8u(f32x4 a, f32x4 b) {
    union { unsigned short us[8]; uint4 u4; } r;
    r.us[0] = f2bf(a[0]); r.us[1] = f2bf(a[1]); r.us[2] = f2bf(a[2]); r.us[3] = f2bf(a[3]);
    r.us[4] = f2bf(b[0]); r.us[5] = f2bf(b[1]); r.us[6] = f2bf(b[2]); r.us[7] = f2bf(b[3]);
    return r.u4;
}

__device__ __forceinline__ bf16x8 pk8(f32x4 a, f32x4 b) {
    union { uint4 u4; bf16x8 v; } r;
    r.u4 = pk8u(a, b);
    return r.v;
}

__device__ __forceinline__ void gl_lds16(const void* g, void* l) {
    __builtin_amdgcn_global_load_lds(
        (const __attribute__((address_space(1))) unsigned int*)g,
        (__attribute__((address_space(3))) unsigned int*)l,
        16, 0, 0);
}

// ---------------------------------------------------------------------------
// 1) merged converts. blocks 0..2047: node_feats -> A_swz bf16 (row-chunk
//    swizzled). blocks 2048..3071: W_obj -> W_T bf16 transposed + swizzled.
__global__ __launch_bounds__(256) void cvt_k(const float* __restrict__ nf,
                                             const float* __restrict__ W,
                                             unsigned short* __restrict__ A,
                                             unsigned short* __restrict__ WT) {
    __shared__ float lds[32][33];
    int bid = blockIdx.x;
    if (bid < 2048) {
        // ---- A convert+swizzle: thread handles 16B-out groups ----
        int tid = bid * 256 + threadIdx.x;            // 524288 threads
        for (int p = tid; p < 1048576; p += 524288) { // 8-elem groups
            int r = p >> 8;                           // row 0..4095
            int grp = p & 255;                        // group within row
            int chunk = grp >> 4, slot = grp & 15;
            int sslot = slot ^ (r & 15);
            const float* src = nf + (size_t)r * 2048 + chunk * 128 + sslot * 8;
            f32x4 v0 = *(const f32x4*)(src);
            f32x4 v1 = *(const f32x4*)(src + 4);
            *(uint4*)(A + (size_t)r * 2048 + chunk * 128 + slot * 8) = pk8u(v0, v1);
        }
    } else {
        // ---- W_T transpose + convert + swizzle ----
        int g = bid - 2048;                           // 0..1023
        int k0 = (g & 63) * 32, n0 = (g >> 6) * 32;
        int tx = threadIdx.x & 31, ty = threadIdx.x >> 5;
#pragma unroll
        for (int j = 0; j < 4; ++j)
            lds[ty + j * 8][tx] = W[(size_t)(k0 + ty + j * 8) * 512 + n0 + tx];
        __syncthreads();
#pragma unroll
        for (int j = 0; j < 4; ++j) {
            int n = n0 + ty + j * 8;
            int k = k0 + tx;
            int chunk = k >> 7, off = k & 127;
            int ksw = chunk * 128 + (((off >> 3) ^ (n & 15)) << 3) + (off & 7);
            WT[(size_t)n * 2048 + ksw] = f2bf(lds[tx][ty + j * 8]);
        }
    }
}

// ---------------------------------------------------------------------------
// gemm1 body: node_h[4096][512](fp32) = relu(A_swz @ W_T^T + b).
// BM=64 BN=64 BK=128, 256 thr (4 waves 2x2 of 32x32), 512 blocks = 2/CU.
// Double-buffered gl_lds LDS (64KB). Swizzled ds_read (conflict-optimal).
// T5: setprio(1) around the MFMA cluster.
__device__ __forceinline__ void gemm1_body(char* smem, int g1, int t,
                                           const unsigned short* __restrict__ A,
                                           const unsigned short* __restrict__ BT,
                                           const float* __restrict__ bias,
                                           float* __restrict__ C) {
    unsigned short* AsmB = (unsigned short*)smem;            // [2][64][128]
    unsigned short* BsmB = (unsigned short*)(smem + 32768);  // [2][64][128]

    // XCD swizzle over 512 gemm1-blocks (bijective).
    int swz = (g1 & 7) * 64 + (g1 >> 3);
    int by = swz >> 3, bx = swz & 7;
    int m0 = by * 64, n0 = bx * 64;

    int lane = t & 63, w = t >> 6;
    int wm = w >> 1, wn = w & 1;              // wave grid 2x2
    int l15 = lane & 15, l16 = lane >> 4;

    // staging: wave w owns A rows [w*16,w*16+16) and B rows same; chunk =
    // 4 rows x 256B; lane l -> row l>>4, 16B slot l&15 (linear = gl_lds).
    int srow = lane >> 4, scol = (lane & 15) * 8;
    const unsigned short* aG = A  + (size_t)(m0 + w * 16 + srow) * 2048 + scol;
    const unsigned short* bG = BT + (size_t)(n0 + w * 16 + srow) * 2048 + scol;

    f32x4 acc[2][2];
#pragma unroll
    for (int i = 0; i < 2; ++i)
#pragma unroll
        for (int j = 0; j < 2; ++j) acc[i][j] = (f32x4){0.f, 0.f, 0.f, 0.f};

#define G1_STAGE(buf, step)                                                    \
    do {                                                                       \
        int _ko = (step) * 128;                                                \
        unsigned short* _aL = AsmB + (buf) * 8192 + (w * 16) * 128;            \
        unsigned short* _bL = BsmB + (buf) * 8192 + (w * 16) * 128;            \
        _Pragma("unroll")                                                      \
        for (int _i = 0; _i < 4; ++_i) {                                       \
            gl_lds16(aG + (size_t)(_i * 4) * 2048 + _ko, _aL + (_i * 4) * 128);\
            gl_lds16(bG + (size_t)(_i * 4) * 2048 + _ko, _bL + (_i * 4) * 128);\
        }                                                                      \
    } while (0)

    G1_STAGE(0, 0);
    __syncthreads();

    for (int s = 0; s < 16; ++s) {
        int cur = s & 1;
        if (s < 15) G1_STAGE(cur ^ 1, s + 1);   // issue next-tile loads first

        const char* Ab = (const char*)(AsmB + cur * 8192);
        const char* Bb = (const char*)(BsmB + cur * 8192);
        __builtin_amdgcn_s_setprio(1);          // T5: favor this wave's MFMAs
#pragma unroll
        for (int ks = 0; ks < 4; ++ks) {
            int co = ks * 64 + l16 * 16;        // byte col within 256B row
            int r0 = wm * 32 + l15, r1 = r0 + 16;
            int c0n = wn * 32 + l15, c1n = c0n + 16;
            bf16x8 a0 = *(const bf16x8*)(Ab + r0 * 256 + (co ^ ((r0 & 15) << 4)));
            bf16x8 a1 = *(const bf16x8*)(Ab + r1 * 256 + (co ^ ((r1 & 15) << 4)));
            bf16x8 b0 = *(const bf16x8*)(Bb + c0n * 256 + (co ^ ((c0n & 15) << 4)));
            bf16x8 b1 = *(const bf16x8*)(Bb + c1n * 256 + (co ^ ((c1n & 15) << 4)));
            acc[0][0] = __builtin_amdgcn_mfma_f32_16x16x32_bf16(a0, b0, acc[0][0], 0, 0, 0);
            acc[0][1] = __builtin_amdgcn_mfma_f32_16x16x32_bf16(a0, b1, acc[0][1], 0, 0, 0);
            acc[1][0] = __builtin_amdgcn_mfma_f32_16x16x32_bf16(a1, b0, acc[1][0], 0, 0, 0);
            acc[1][1] = __builtin_amdgcn_mfma_f32_16x16x32_bf16(a1, b1, acc[1][1], 0, 0, 0);
        }
        __builtin_amdgcn_s_setprio(0);
        __syncthreads();
    }
#undef G1_STAGE

    // epilogue: bias + relu -> fp32; D layout col=lane&15, row=(lane>>4)*4+j
#pragma unroll
    for (int fm = 0; fm < 2; ++fm)
#pragma unroll
        for (int fn = 0; fn < 2; ++fn) {
            int col = n0 + wn * 32 + fn * 16 + l15;
            float bv = bias[col];
#pragma unroll
            for (int j = 0; j < 4; ++j) {
                int row = m0 + wm * 32 + fm * 16 + l16 * 4 + j;
                float v = acc[fm][fn][j] + bv;
                C[(size_t)row * 512 + col] = v > 0.f ? v : 0.f;
            }
        }
}

// ---------------------------------------------------------------------------
// gemm2 body: part[z][64][4096], single-pass W_q. bid2 0..255:
// c0 = (bid2&31)*128, z = bid2>>5. 256 thr (4 waves).
#define LDK2 136
__device__ __forceinline__ void gemm2_body(char* smem, int bid2, int t,
                                           const float* __restrict__ qf,
                                           const float* __restrict__ Wq,
                                           float* __restrict__ part) {
    auto Asm = reinterpret_cast<unsigned short(*)[LDK2]>(smem);                 // [64][136]
    auto Bsm = reinterpret_cast<unsigned short(*)[LDK2]>(smem + 64 * LDK2 * 2); // [128][136]

    int lane = t & 63, w = t >> 6;
    int l15 = lane & 15, l16 = lane >> 4;
    int c0 = (bid2 & 31) * 128;
    int k0 = (bid2 >> 5) * 128;

#pragma unroll
    for (int j = 0; j < 4; ++j) {
        int g = t + j * 256;
        int row = g >> 4, kc = g & 15;
        const float* src = qf + (size_t)row * 1024 + k0 + kc * 8;
        f32x4 v0 = *(const f32x4*)(src);
        f32x4 v1 = *(const f32x4*)(src + 4);
        *(uint4*)(&Asm[row][kc * 8]) = pk8u(v0, v1);
    }
#pragma unroll
    for (int j = 0; j < 2; ++j) {
        int g = t + j * 256;
        int kg = g >> 5, cg = g & 31;
        f32x4 wv[8];
#pragma unroll
        for (int kk = 0; kk < 8; ++kk)
            wv[kk] = *(const f32x4*)(Wq + (size_t)(k0 + kg * 8 + kk) * 4096 + c0 + cg * 4);
#pragma unroll
        for (int cc = 0; cc < 4; ++cc) {
            union { unsigned short us[8]; uint4 u4; } p;
#pragma unroll
            for (int kk = 0; kk < 8; ++kk) p.us[kk] = f2bf(wv[kk][cc]);
            *(uint4*)(&Bsm[cg * 4 + cc][kg * 8]) = p.u4;
        }
    }
    __syncthreads();

    f32x4 acc[4][2];
#pragma unroll
    for (int i = 0; i < 4; ++i)
#pragma unroll
        for (int j = 0; j < 2; ++j) acc[i][j] = (f32x4){0.f, 0.f, 0.f, 0.f};

#pragma unroll
    for (int ks = 0; ks < 4; ++ks) {
        bf16x8 bfr[2];
#pragma unroll
        for (int jn = 0; jn < 2; ++jn)
            bfr[jn] = *(const bf16x8*)(&Bsm[w * 32 + jn * 16 + l15][ks * 32 + l16 * 8]);
#pragma unroll
        for (int i = 0; i < 4; ++i) {
            bf16x8 afr = *(const bf16x8*)(&Asm[i * 16 + l15][ks * 32 + l16 * 8]);
            acc[i][0] = __builtin_amdgcn_mfma_f32_16x16x32_bf16(afr, bfr[0], acc[i][0], 0, 0, 0);
            acc[i][1] = __builtin_amdgcn_mfma_f32_16x16x32_bf16(afr, bfr[1], acc[i][1], 0, 0, 0);
        }
    }

    float* pz = part + (size_t)(bid2 >> 5) * 262144;
#pragma unroll
    for (int i = 0; i < 4; ++i)
#pragma unroll
        for (int jn = 0; jn < 2; ++jn) {
            int col = c0 + w * 32 + jn * 16 + l15;
#pragma unroll
            for (int j = 0; j < 4; ++j) {
                int row = i * 16 + l16 * 4 + j;
                pz[(size_t)row * 4096 + col] = acc[i][jn][j];
            }
        }
}

// ---------------------------------------------------------------------------
// 2) fused: blocks 0..255 gemm2, 256..767 gemm1 (concurrent, no aliasing).
//    Heterogeneous pairing: gemm2's latency-bound waves fill gemm1's
//    barrier-drain stalls; early gemm2 completion staggers gemm1 starts.
__global__ __launch_bounds__(256) void gemm_fused(const unsigned short* A,
                                                  const unsigned short* BT,
                                                  const float* bias, float* C,
                                                  const float* qf, const float* Wq,
                                                  float* part) {
    __shared__ __align__(16) char smem[65536];
    int bid = blockIdx.x, t = threadIdx.x;
    if (bid < 256) gemm2_body(smem, bid, t, qf, Wq, part);
    else           gemm1_body(smem, bid - 256, t, A, BT, bias, C);
}
// fallback wrappers (sequential path if ws too small for un-aliased part)
__global__ __launch_bounds__(256) void gemm1_only(const unsigned short* A,
                                                  const unsigned short* BT,
                                                  const float* bias, float* C) {
    __shared__ __align__(16) char smem[65536];
    gemm1_body(smem, blockIdx.x, threadIdx.x, A, BT, bias, C);
}
__global__ __launch_bounds__(256) void gemm2_only(const float* qf, const float* Wq,
                                                  float* part) {
    __shared__ __align__(16) char smem[65536];
    gemm2_body(smem, blockIdx.x, threadIdx.x, qf, Wq, part);
}

// ---------------------------------------------------------------------------
// 3) tail_k: one block per batch (64 x 256 thr). reduce+bias+relu -> norms ->
//    P-MFMA -> 512 edge gather-adds.
__global__ __launch_bounds__(256) void tail_k(const float* __restrict__ part,
                                              const float* __restrict__ bq,
                                              const float* __restrict__ node_h,
                                              const int* __restrict__ idxs,
                                              float* __restrict__ out) {
    __shared__ float qs[4096];
    __shared__ float red[4][8];
    __shared__ float inv[8];
    __shared__ float Pl[64][8];

    int b = blockIdx.x, t = threadIdx.x;
    int lane = t & 63, w = t >> 6;
    int l15 = lane & 15, l16 = lane >> 4;

    // ---- phase 1: reduce k-split partials + bias + relu ----
#pragma unroll
    for (int j = 0; j < 4; ++j) {
        int c = j * 1024 + t * 4;
        f32x4 a = (f32x4){0.f, 0.f, 0.f, 0.f};
#pragma unroll
        for (int z = 0; z < 8; ++z)
            a += *(const f32x4*)(part + (size_t)z * 262144 + (size_t)b * 4096 + c);
        f32x4 bb = *(const f32x4*)(bq + c);
#pragma unroll
        for (int i = 0; i < 4; ++i) {
            float v = a[i] + bb[i];
            a[i] = v > 0.f ? v : 0.f;
        }
        *(f32x4*)(&qs[c]) = a;
    }
    __syncthreads();

    // ---- phase 2: per-k norms ----
    {
        const float* row = qs + t * 16;
        float sq[8] = {0.f, 0.f, 0.f, 0.f, 0.f, 0.f, 0.f, 0.f};
#pragma unroll
        for (int j = 0; j < 4; ++j) {
            f32x4 v = *(const f32x4*)(row + j * 4);
            sq[(j * 4 + 0) & 7] += v[0] * v[0];
            sq[(j * 4 + 1) & 7] += v[1] * v[1];
            sq[(j * 4 + 2) & 7] += v[2] * v[2];
            sq[(j * 4 + 3) & 7] += v[3] * v[3];
        }
#pragma unroll
        for (int k = 0; k < 8; ++k) {
            float v = sq[k];
            v += __shfl_xor(v, 1);  v += __shfl_xor(v, 2);  v += __shfl_xor(v, 4);
            v += __shfl_xor(v, 8);  v += __shfl_xor(v, 16); v += __shfl_xor(v, 32);
            sq[k] = v;
        }
        if (lane == 0) {
#pragma unroll
            for (int k = 0; k < 8; ++k) red[w][k] = sq[k];
        }
    }
    __syncthreads();
    if (t < 8) {
        float s = red[0][t] + red[1][t] + red[2][t] + red[3][t];
        inv[t] = 1.0f / sqrtf(s);
    }
    __syncthreads();

    // ---- phase 3: P = (node_h[b] @ q_e) * inv  (MFMA 16x16x32, N=8 used) --
    {
        bool active = l15 < 8;
        float invv = active ? inv[l15] : 0.f;
        const float* arow = node_h + (size_t)(b * 64 + w * 16 + l15) * 512 + l16 * 8;
        f32x4 acc = (f32x4){0.f, 0.f, 0.f, 0.f};
#pragma unroll
        for (int kt = 0; kt < 16; ++kt) {
            f32x4 v0 = *(const f32x4*)(arow + kt * 32);
            f32x4 v1 = *(const f32x4*)(arow + kt * 32 + 4);
            bf16x8 af = pk8(v0, v1);
            union { unsigned short us[8]; bf16x8 v; } bqf;
#pragma unroll
            for (int i = 0; i < 8; ++i)
                bqf.us[i] = active ? f2bf(qs[kt * 256 + (l16 * 8 + i) * 8 + l15]) : 0;
            acc = __builtin_amdgcn_mfma_f32_16x16x32_bf16(af, bqf.v, acc, 0, 0, 0);
        }
        if (active) {
#pragma unroll
            for (int j = 0; j < 4; ++j)
                Pl[w * 16 + l16 * 4 + j][l15] = acc[j] * invv;
        }
    }
    __syncthreads();

    // ---- phase 4: 512 edges of batch b, 2 per thread ----
#pragma unroll
    for (int e = 0; e < 2; ++e) {
        int m = b * 512 + e * 256 + t;
        int idx = idxs[m];
        int r = idx & 4095;
        int src = r >> 6, dst = r & 63;
        f32x4 o0 = *(const f32x4*)(&Pl[src][0]) + *(const f32x4*)(&Pl[dst][0]);
        f32x4 o1 = *(const f32x4*)(&Pl[src][4]) + *(const f32x4*)(&Pl[dst][4]);
        *(f32x4*)(out + (size_t)m * 8)     = o0;
        *(f32x4*)(out + (size_t)m * 8 + 4) = o1;
    }
}

// ---------------------------------------------------------------------------
extern "C" void kernel_launch(void* const* d_in, const int* in_sizes, int n_in,
                              void* d_out, int out_size, void* d_ws, size_t ws_size,
                              hipStream_t stream) {
    const float* node_feats = (const float*)d_in[0];  // [64][64][2048]
    const float* q_feats    = (const float*)d_in[1];  // [64][1024]
    const int*   indexes    = (const int*)d_in[2];    // [32768]
    const float* W_obj      = (const float*)d_in[3];  // [2048][512]
    const float* b_obj      = (const float*)d_in[4];  // [512]
    const float* W_q        = (const float*)d_in[5];  // [1024][4096]
    const float* b_q        = (const float*)d_in[6];  // [4096]
    float* out = (float*)d_out;                       // [32768][8]

    char* ws = (char*)d_ws;
    unsigned short* A_swz = (unsigned short*)(ws + 0);         // 16.78MB
    unsigned short* W_T   = (unsigned short*)(ws + 16777216);  // 2.10MB
    float* node_h         = (float*)(ws + 18874368);           // 8.39MB

    if (ws_size >= 35651584ull) {
        // concurrent layout: part has its own region (no aliasing with A_swz)
        float* part = (float*)(ws + 27262976);                 // 8.39MB
        cvt_k<<<3072, 256, 0, stream>>>(node_feats, W_obj, A_swz, W_T);
        gemm_fused<<<768, 256, 0, stream>>>(A_swz, W_T, b_obj, node_h,
                                            q_feats, W_q, part);
        tail_k<<<64, 256, 0, stream>>>(part, b_q, node_h, indexes, out);
    } else {
        // sequential fallback: part aliases A_swz (gemm2 after gemm1)
        float* part = (float*)(ws + 0);
        cvt_k<<<3072, 256, 0, stream>>>(node_feats, W_obj, A_swz, W_T);
        gemm1_only<<<512, 256, 0, stream>>>(A_swz, W_T, b_obj, node_h);
        gemm2_only<<<256, 256, 0, stream>>>(q_feats, W_q, part);
        tail_k<<<64, 256, 0, stream>>>(part, b_q, node_h, indexes, out);
    }
}

// Round 16
// 42.761 us; speedup vs baseline: 1.4397x; 1.0149x over previous
//
#include <hip/hip_runtime.h>
#include <hip/hip_bf16.h>

// Problem constants (EdgeQProj): B=64, N=64, E=512, OBJ_DIM=2048, Q_DIM=1024,
// HID=512, KS=8. M_edges = B*E = 32768.
//
// R16 = R15 structure with gemm1 rebuilt as a T4 counted-vmcnt pipeline:
//   - triple-buffered LDS (BK=64, 48KB), 2-deep prefetch
//   - raw s_barrier + per-wave s_waitcnt vmcnt(4) (never 0 in steady state)
//   - fused smem 52.2KB -> 3 blocks/CU -> all 768 blocks co-resident
//
// Pipeline (identity: edge_logit[m] = P[b,src]+P[b,dst]):
//   cvt_k     : node_feats -> A_bf16 (8-slot swizzle), W_obj -> W_T (swizzled)
//   gemm_fused: blocks 0-255 = gemm2 (q partials), 256-767 = gemm1 (node_h)
//   tail_k    : per-batch reduce+bias+relu -> norms -> P-MFMA -> edges
//
// Swizzle (rule #21, both-sides, BK=64): within each 64-elem (128B) k-chunk
// of a row, 16B slot g holds data of slot g ^ (row&7). gl_lds copies
// linearly; gemm1's ds_read applies the same XOR.

using bf16x8 = __attribute__((ext_vector_type(8))) __bf16;
using f32x4  = __attribute__((ext_vector_type(4))) float;

__device__ __forceinline__ unsigned short f2bf(float f) {
    unsigned int u = __float_as_uint(f);
    unsigned int r = (u + 0x7FFFu + ((u >> 16) & 1u)) >> 16;  // RNE
    return (unsigned short)r;
}

__device__ __forceinline__ uint4 pk8u(f32x4 a, f32x4 b) {
    union { unsigned short us[8]; uint4 u4; } r;
    r.us[0] = f2bf(a[0]); r.us[1] = f2bf(a[1]); r.us[2] = f2bf(a[2]); r.us[3] = f2bf(a[3]);
    r.us[4] = f2bf(b[0]); r.us[5] = f2bf(b[1]); r.us[6] = f2bf(b[2]); r.us[7] = f2bf(b[3]);
    return r.u4;
}

__device__ __forceinline__ bf16x8 pk8(f32x4 a, f32x4 b) {
    union { uint4 u4; bf16x8 v; } r;
    r.u4 = pk8u(a, b);
    return r.v;
}

__device__ __forceinline__ void gl_lds16(const void* g, void* l) {
    __builtin_amdgcn_global_load_lds(
        (const __attribute__((address_space(1))) unsigned int*)g,
        (__attribute__((address_space(3))) unsigned int*)l,
        16, 0, 0);
}

// ---------------------------------------------------------------------------
// 1) merged converts (R12-verified 8-slot swizzle).
//    blocks 0..2047: node_feats -> A_swz bf16. 2048..3071: W_obj -> W_T.
__global__ __launch_bounds__(256) void cvt_k(const float* __restrict__ nf,
                                             const float* __restrict__ W,
                                             unsigned short* __restrict__ A,
                                             unsigned short* __restrict__ WT) {
    __shared__ float lds[32][33];
    int bid = blockIdx.x;
    if (bid < 2048) {
        // ---- A convert+swizzle: chunk=64 elems, 8 slots, slot^=(row&7) ----
        int tid = bid * 256 + threadIdx.x;            // 524288 threads
        for (int p = tid; p < 1048576; p += 524288) {
            int r = p >> 8;                           // row 0..4095
            int grp = p & 255;                        // 8-elem group in row
            int chunk = grp >> 3, slot = grp & 7;
            int sslot = slot ^ (r & 7);
            const float* src = nf + (size_t)r * 2048 + chunk * 64 + sslot * 8;
            f32x4 v0 = *(const f32x4*)(src);
            f32x4 v1 = *(const f32x4*)(src + 4);
            *(uint4*)(A + (size_t)r * 2048 + chunk * 64 + slot * 8) = pk8u(v0, v1);
        }
    } else {
        // ---- W_T transpose + convert + swizzle ----
        int g = bid - 2048;                           // 0..1023
        int k0 = (g & 63) * 32, n0 = (g >> 6) * 32;
        int tx = threadIdx.x & 31, ty = threadIdx.x >> 5;
#pragma unroll
        for (int j = 0; j < 4; ++j)
            lds[ty + j * 8][tx] = W[(size_t)(k0 + ty + j * 8) * 512 + n0 + tx];
        __syncthreads();
#pragma unroll
        for (int j = 0; j < 4; ++j) {
            int n = n0 + ty + j * 8;
            int k = k0 + tx;
            int chunk = k >> 6, off = k & 63;
            int ksw = chunk * 64 + (((off >> 3) ^ (n & 7)) << 3) + (k & 7);
            WT[(size_t)n * 2048 + ksw] = f2bf(lds[tx][ty + j * 8]);
        }
    }
}

// ---------------------------------------------------------------------------
// gemm1 body (T4 counted-vmcnt): node_h[4096][512](fp32) = relu(A@W^T + b).
// BM=64 BN=64 BK=64, 256 thr (4 waves 2x2, wave tile 32x32), 512 blocks.
// TRIPLE-buffered LDS (48KB), 2-deep prefetch:
//   invariant at step-s top: stage(s) globally complete.
//   body: issue STAGE(s+2); ds_read+MFMA buf[s%3];
//         s_waitcnt vmcnt(4)   (own stage(s+1) loads done; issued 1 full
//                               step earlier -> ~2 compute phases of cover)
//         sched_barrier; s_barrier; sched_barrier   (global completeness;
//                               fences stop hipcc hoisting loads across)
// Write-after-read safety: STAGE(s+2) writes buf[(s-1)%3], whose readers all
// passed the step-(s-1) barrier (which follows their reads).
__device__ __forceinline__ void gemm1_body(char* smem, int g1, int t,
                                           const unsigned short* __restrict__ A,
                                           const unsigned short* __restrict__ BT,
                                           const float* __restrict__ bias,
                                           float* __restrict__ C) {
    unsigned short* AsmB = (unsigned short*)smem;            // [3][64][64]
    unsigned short* BsmB = (unsigned short*)(smem + 24576);  // [3][64][64]

    // XCD swizzle over 512 gemm1-blocks (bijective): per-XCD 8 m-panels + B.
    int swz = (g1 & 7) * 64 + (g1 >> 3);
    int by = swz >> 3, bx = swz & 7;
    int m0 = by * 64, n0 = bx * 64;

    int lane = t & 63, w = t >> 6;
    int wm = w >> 1, wn = w & 1;              // wave grid 2x2
    int l15 = lane & 15, l16 = lane >> 4;

    // staging: chunk = 8 rows x 128B; lane l -> row l>>3, slot l&7 (linear).
    // wave w owns A rows [w*16,w*16+16) and B rows [w*16,w*16+16), 2 chunks ea.
    const unsigned short* aG = A  + (size_t)(m0 + w * 16 + (lane >> 3)) * 2048 + (lane & 7) * 8;
    const unsigned short* bG = BT + (size_t)(n0 + w * 16 + (lane >> 3)) * 2048 + (lane & 7) * 8;

    f32x4 acc[2][2];
#pragma unroll
    for (int i = 0; i < 2; ++i)
#pragma unroll
        for (int j = 0; j < 2; ++j) acc[i][j] = (f32x4){0.f, 0.f, 0.f, 0.f};

#define G1_STAGE(buf, step)                                                    \
    do {                                                                       \
        int _ko = (step) * 64;                                                 \
        unsigned short* _aL = AsmB + (buf) * 4096 + (w * 16) * 64;             \
        unsigned short* _bL = BsmB + (buf) * 4096 + (w * 16) * 64;             \
        gl_lds16(aG + _ko, _aL);                                               \
        gl_lds16(aG + (size_t)8 * 2048 + _ko, _aL + 512);                      \
        gl_lds16(bG + _ko, _bL);                                               \
        gl_lds16(bG + (size_t)8 * 2048 + _ko, _bL + 512);                      \
    } while (0)

    // prologue: 2 stages in flight; establish invariant for s=0
    G1_STAGE(0, 0);
    G1_STAGE(1, 1);
    asm volatile("s_waitcnt vmcnt(4)" ::: "memory");   // own stage0 done
    __builtin_amdgcn_sched_barrier(0);
    __builtin_amdgcn_s_barrier();                       // -> global
    __builtin_amdgcn_sched_barrier(0);

    int buf = 0;
    for (int s = 0; s < 32; ++s) {
        if (s < 30) {
            int nb = buf + 2; if (nb >= 3) nb -= 3;
            G1_STAGE(nb, s + 2);                        // 2-deep prefetch
        }

        const char* Ab = (const char*)(AsmB + buf * 4096);
        const char* Bb = (const char*)(BsmB + buf * 4096);
        int r0 = wm * 32 + l15, r1 = r0 + 16;
        int c0n = wn * 32 + l15, c1n = c0n + 16;
        __builtin_amdgcn_s_setprio(1);
#pragma unroll
        for (int ks = 0; ks < 2; ++ks) {
            int sx = ((ks * 4 + l16) ^ (l15 & 7)) << 4; // swizzled byte slot
            bf16x8 a0 = *(const bf16x8*)(Ab + r0 * 128 + sx);
            bf16x8 a1 = *(const bf16x8*)(Ab + r1 * 128 + sx);
            bf16x8 b0 = *(const bf16x8*)(Bb + c0n * 128 + sx);
            bf16x8 b1 = *(const bf16x8*)(Bb + c1n * 128 + sx);
            acc[0][0] = __builtin_amdgcn_mfma_f32_16x16x32_bf16(a0, b0, acc[0][0], 0, 0, 0);
            acc[0][1] = __builtin_amdgcn_mfma_f32_16x16x32_bf16(a0, b1, acc[0][1], 0, 0, 0);
            acc[1][0] = __builtin_amdgcn_mfma_f32_16x16x32_bf16(a1, b0, acc[1][0], 0, 0, 0);
            acc[1][1] = __builtin_amdgcn_mfma_f32_16x16x32_bf16(a1, b1, acc[1][1], 0, 0, 0);
        }
        __builtin_amdgcn_s_setprio(0);

        if (s < 31) {
            if (s < 30) asm volatile("s_waitcnt vmcnt(4)" ::: "memory");
            else        asm volatile("s_waitcnt vmcnt(0)" ::: "memory");
            __builtin_amdgcn_sched_barrier(0);
            __builtin_amdgcn_s_barrier();
            __builtin_amdgcn_sched_barrier(0);
        }
        buf = (buf == 2) ? 0 : buf + 1;
    }
#undef G1_STAGE

    // epilogue: bias + relu -> fp32; D layout col=lane&15, row=(lane>>4)*4+j
#pragma unroll
    for (int fm = 0; fm < 2; ++fm)
#pragma unroll
        for (int fn = 0; fn < 2; ++fn) {
            int col = n0 + wn * 32 + fn * 16 + l15;
            float bv = bias[col];
#pragma unroll
            for (int j = 0; j < 4; ++j) {
                int row = m0 + wm * 32 + fm * 16 + l16 * 4 + j;
                float v = acc[fm][fn][j] + bv;
                C[(size_t)row * 512 + col] = v > 0.f ? v : 0.f;
            }
        }
}

// ---------------------------------------------------------------------------
// gemm2 body (unchanged, proven): part[z][64][4096], single-pass W_q.
// bid2 0..255: c0 = (bid2&31)*128, z = bid2>>5. 256 thr (4 waves).
#define LDK2 136
__device__ __forceinline__ void gemm2_body(char* smem, int bid2, int t,
                                           const float* __restrict__ qf,
                                           const float* __restrict__ Wq,
                                           float* __restrict__ part) {
    auto Asm = reinterpret_cast<unsigned short(*)[LDK2]>(smem);                 // [64][136]
    auto Bsm = reinterpret_cast<unsigned short(*)[LDK2]>(smem + 64 * LDK2 * 2); // [128][136]

    int lane = t & 63, w = t >> 6;
    int l15 = lane & 15, l16 = lane >> 4;
    int c0 = (bid2 & 31) * 128;
    int k0 = (bid2 >> 5) * 128;

#pragma unroll
    for (int j = 0; j < 4; ++j) {
        int g = t + j * 256;
        int row = g >> 4, kc = g & 15;
        const float* src = qf + (size_t)row * 1024 + k0 + kc * 8;
        f32x4 v0 = *(const f32x4*)(src);
        f32x4 v1 = *(const f32x4*)(src + 4);
        *(uint4*)(&Asm[row][kc * 8]) = pk8u(v0, v1);
    }
#pragma unroll
    for (int j = 0; j < 2; ++j) {
        int g = t + j * 256;
        int kg = g >> 5, cg = g & 31;
        f32x4 wv[8];
#pragma unroll
        for (int kk = 0; kk < 8; ++kk)
            wv[kk] = *(const f32x4*)(Wq + (size_t)(k0 + kg * 8 + kk) * 4096 + c0 + cg * 4);
#pragma unroll
        for (int cc = 0; cc < 4; ++cc) {
            union { unsigned short us[8]; uint4 u4; } p;
#pragma unroll
            for (int kk = 0; kk < 8; ++kk) p.us[kk] = f2bf(wv[kk][cc]);
            *(uint4*)(&Bsm[cg * 4 + cc][kg * 8]) = p.u4;
        }
    }
    __syncthreads();

    f32x4 acc[4][2];
#pragma unroll
    for (int i = 0; i < 4; ++i)
#pragma unroll
        for (int j = 0; j < 2; ++j) acc[i][j] = (f32x4){0.f, 0.f, 0.f, 0.f};

#pragma unroll
    for (int ks = 0; ks < 4; ++ks) {
        bf16x8 bfr[2];
#pragma unroll
        for (int jn = 0; jn < 2; ++jn)
            bfr[jn] = *(const bf16x8*)(&Bsm[w * 32 + jn * 16 + l15][ks * 32 + l16 * 8]);
#pragma unroll
        for (int i = 0; i < 4; ++i) {
            bf16x8 afr = *(const bf16x8*)(&Asm[i * 16 + l15][ks * 32 + l16 * 8]);
            acc[i][0] = __builtin_amdgcn_mfma_f32_16x16x32_bf16(afr, bfr[0], acc[i][0], 0, 0, 0);
            acc[i][1] = __builtin_amdgcn_mfma_f32_16x16x32_bf16(afr, bfr[1], acc[i][1], 0, 0, 0);
        }
    }

    float* pz = part + (size_t)(bid2 >> 5) * 262144;
#pragma unroll
    for (int i = 0; i < 4; ++i)
#pragma unroll
        for (int jn = 0; jn < 2; ++jn) {
            int col = c0 + w * 32 + jn * 16 + l15;
#pragma unroll
            for (int j = 0; j < 4; ++j) {
                int row = i * 16 + l16 * 4 + j;
                pz[(size_t)row * 4096 + col] = acc[i][jn][j];
            }
        }
}

// ---------------------------------------------------------------------------
// 2) fused: blocks 0..255 gemm2, 256..767 gemm1. smem 52.2KB -> 3 blocks/CU
//    -> all 768 blocks co-resident in one scheduling round.
__global__ __launch_bounds__(256) void gemm_fused(const unsigned short* A,
                                                  const unsigned short* BT,
                                                  const float* bias, float* C,
                                                  const float* qf, const float* Wq,
                                                  float* part) {
    __shared__ __align__(16) char smem[52224];   // max(gemm1 48K, gemm2 51K)
    int bid = blockIdx.x, t = threadIdx.x;
    if (bid < 256) gemm2_body(smem, bid, t, qf, Wq, part);
    else           gemm1_body(smem, bid - 256, t, A, BT, bias, C);
}
// fallback wrappers (sequential path if ws too small for un-aliased part)
__global__ __launch_bounds__(256) void gemm1_only(const unsigned short* A,
                                                  const unsigned short* BT,
                                                  const float* bias, float* C) {
    __shared__ __align__(16) char smem[52224];
    gemm1_body(smem, blockIdx.x, threadIdx.x, A, BT, bias, C);
}
__global__ __launch_bounds__(256) void gemm2_only(const float* qf, const float* Wq,
                                                  float* part) {
    __shared__ __align__(16) char smem[52224];
    gemm2_body(smem, blockIdx.x, threadIdx.x, qf, Wq, part);
}

// ---------------------------------------------------------------------------
// 3) tail_k: one block per batch (64 x 256 thr). reduce+bias+relu -> norms ->
//    P-MFMA -> 512 edge gather-adds.
__global__ __launch_bounds__(256) void tail_k(const float* __restrict__ part,
                                              const float* __restrict__ bq,
                                              const float* __restrict__ node_h,
                                              const int* __restrict__ idxs,
                                              float* __restrict__ out) {
    __shared__ float qs[4096];
    __shared__ float red[4][8];
    __shared__ float inv[8];
    __shared__ float Pl[64][8];

    int b = blockIdx.x, t = threadIdx.x;
    int lane = t & 63, w = t >> 6;
    int l15 = lane & 15, l16 = lane >> 4;

    // ---- phase 1: reduce k-split partials + bias + relu ----
#pragma unroll
    for (int j = 0; j < 4; ++j) {
        int c = j * 1024 + t * 4;
        f32x4 a = (f32x4){0.f, 0.f, 0.f, 0.f};
#pragma unroll
        for (int z = 0; z < 8; ++z)
            a += *(const f32x4*)(part + (size_t)z * 262144 + (size_t)b * 4096 + c);
        f32x4 bb = *(const f32x4*)(bq + c);
#pragma unroll
        for (int i = 0; i < 4; ++i) {
            float v = a[i] + bb[i];
            a[i] = v > 0.f ? v : 0.f;
        }
        *(f32x4*)(&qs[c]) = a;
    }
    __syncthreads();

    // ---- phase 2: per-k norms ----
    {
        const float* row = qs + t * 16;
        float sq[8] = {0.f, 0.f, 0.f, 0.f, 0.f, 0.f, 0.f, 0.f};
#pragma unroll
        for (int j = 0; j < 4; ++j) {
            f32x4 v = *(const f32x4*)(row + j * 4);
            sq[(j * 4 + 0) & 7] += v[0] * v[0];
            sq[(j * 4 + 1) & 7] += v[1] * v[1];
            sq[(j * 4 + 2) & 7] += v[2] * v[2];
            sq[(j * 4 + 3) & 7] += v[3] * v[3];
        }
#pragma unroll
        for (int k = 0; k < 8; ++k) {
            float v = sq[k];
            v += __shfl_xor(v, 1);  v += __shfl_xor(v, 2);  v += __shfl_xor(v, 4);
            v += __shfl_xor(v, 8);  v += __shfl_xor(v, 16); v += __shfl_xor(v, 32);
            sq[k] = v;
        }
        if (lane == 0) {
#pragma unroll
            for (int k = 0; k < 8; ++k) red[w][k] = sq[k];
        }
    }
    __syncthreads();
    if (t < 8) {
        float s = red[0][t] + red[1][t] + red[2][t] + red[3][t];
        inv[t] = 1.0f / sqrtf(s);
    }
    __syncthreads();

    // ---- phase 3: P = (node_h[b] @ q_e) * inv  (MFMA 16x16x32, N=8 used) --
    {
        bool active = l15 < 8;
        float invv = active ? inv[l15] : 0.f;
        const float* arow = node_h + (size_t)(b * 64 + w * 16 + l15) * 512 + l16 * 8;
        f32x4 acc = (f32x4){0.f, 0.f, 0.f, 0.f};
#pragma unroll
        for (int kt = 0; kt < 16; ++kt) {
            f32x4 v0 = *(const f32x4*)(arow + kt * 32);
            f32x4 v1 = *(const f32x4*)(arow + kt * 32 + 4);
            bf16x8 af = pk8(v0, v1);
            union { unsigned short us[8]; bf16x8 v; } bqf;
#pragma unroll
            for (int i = 0; i < 8; ++i)
                bqf.us[i] = active ? f2bf(qs[kt * 256 + (l16 * 8 + i) * 8 + l15]) : 0;
            acc = __builtin_amdgcn_mfma_f32_16x16x32_bf16(af, bqf.v, acc, 0, 0, 0);
        }
        if (active) {
#pragma unroll
            for (int j = 0; j < 4; ++j)
                Pl[w * 16 + l16 * 4 + j][l15] = acc[j] * invv;
        }
    }
    __syncthreads();

    // ---- phase 4: 512 edges of batch b, 2 per thread ----
#pragma unroll
    for (int e = 0; e < 2; ++e) {
        int m = b * 512 + e * 256 + t;
        int idx = idxs[m];
        int r = idx & 4095;
        int src = r >> 6, dst = r & 63;
        f32x4 o0 = *(const f32x4*)(&Pl[src][0]) + *(const f32x4*)(&Pl[dst][0]);
        f32x4 o1 = *(const f32x4*)(&Pl[src][4]) + *(const f32x4*)(&Pl[dst][4]);
        *(f32x4*)(out + (size_t)m * 8)     = o0;
        *(f32x4*)(out + (size_t)m * 8 + 4) = o1;
    }
}

// ---------------------------------------------------------------------------
extern "C" void kernel_launch(void* const* d_in, const int* in_sizes, int n_in,
                              void* d_out, int out_size, void* d_ws, size_t ws_size,
                              hipStream_t stream) {
    const float* node_feats = (const float*)d_in[0];  // [64][64][2048]
    const float* q_feats    = (const float*)d_in[1];  // [64][1024]
    const int*   indexes    = (const int*)d_in[2];    // [32768]
    const float* W_obj      = (const float*)d_in[3];  // [2048][512]
    const float* b_obj      = (const float*)d_in[4];  // [512]
    const float* W_q        = (const float*)d_in[5];  // [1024][4096]
    const float* b_q        = (const float*)d_in[6];  // [4096]
    float* out = (float*)d_out;                       // [32768][8]

    char* ws = (char*)d_ws;
    unsigned short* A_swz = (unsigned short*)(ws + 0);         // 16.78MB
    unsigned short* W_T   = (unsigned short*)(ws + 16777216);  // 2.10MB
    float* node_h         = (float*)(ws + 18874368);           // 8.39MB

    if (ws_size >= 35651584ull) {
        // concurrent layout: part has its own region (no aliasing with A_swz)
        float* part = (float*)(ws + 27262976);                 // 8.39MB
        cvt_k<<<3072, 256, 0, stream>>>(node_feats, W_obj, A_swz, W_T);
        gemm_fused<<<768, 256, 0, stream>>>(A_swz, W_T, b_obj, node_h,
                                            q_feats, W_q, part);
        tail_k<<<64, 256, 0, stream>>>(part, b_q, node_h, indexes, out);
    } else {
        // sequential fallback: part aliases A_swz (gemm2 after gemm1)
        float* part = (float*)(ws + 0);
        cvt_k<<<3072, 256, 0, stream>>>(node_feats, W_obj, A_swz, W_T);
        gemm1_only<<<512, 256, 0, stream>>>(A_swz, W_T, b_obj, node_h);
        gemm2_only<<<256, 256, 0, stream>>>(q_feats, W_q, part);
        tail_k<<<64, 256, 0, stream>>>(part, b_q, node_h, indexes, out);
    }
}